// Round 19
// baseline (189.888 us; speedup 1.0000x reference)
//
#include <hip/hip_runtime.h>
#include <hip/hip_fp16.h>

#define NN 50000
#define NE 800000
#define NG 128
#define IND 5
#define HID 64
#define EPSV 1e-5f

#define NB 391          // buckets of 128 nodes: 391*128 = 50048 >= 50001
#define PH_T 256        // partition wg size (was 1024 — 8 blocks/CU now fit)
#define PH_E 2048       // edges per partition wg
#define PH_WG ((NE + PH_E - 1) / PH_E)   // 391 wgs (~1.5/CU, 10x the waves)

// ---- partition pass 1: per-WG bucket histogram slices; also zeroes pool/cnt ----
__global__ void k_part_hist(const int* __restrict__ dst, int* __restrict__ h_wg,
                            float* __restrict__ pool_zero) {
    __shared__ int h[NB];
    int tid = threadIdx.x;
    int zgid = blockIdx.x * PH_T + tid;
    if (zgid < NG * HID + NG) pool_zero[zgid] = 0.f;
    for (int j = tid; j < NB; j += PH_T) h[j] = 0;
    __syncthreads();
    int base = blockIdx.x * PH_E;
    for (int k = 0; k < PH_E; k += PH_T) {
        int e = base + k + tid;
        if (e < NE) atomicAdd(&h[dst[e] >> 7], 1);
    }
    __syncthreads();
    for (int j = tid; j < NB; j += PH_T) h_wg[blockIdx.x * NB + j] = h[j];
}

// ---- scan: bucket totals -> beb; column prefix -> per-WG bases ----
__global__ void k_bscan(const int* __restrict__ h_wg, int* __restrict__ wgbase,
                        int* __restrict__ beb) {
    __shared__ int sm[512];
    int t = threadIdx.x;
    int tot = 0;
    if (t < NB) {
        for (int w = 0; w < PH_WG; w++) {
            wgbase[w * NB + t] = tot;
            tot += h_wg[w * NB + t];
        }
    }
    sm[t] = (t < NB) ? tot : 0;
    __syncthreads();
    for (int off = 1; off < 512; off <<= 1) {
        int v = (t >= off) ? sm[t - off] : 0;
        __syncthreads();
        sm[t] += v;
        __syncthreads();
    }
    if (t <= NB) beb[t] = t ? sm[t - 1] : 0;
    if (t < NB) {
        int base = t ? sm[t - 1] : 0;
        for (int w = 0; w < PH_WG; w++) wgbase[w * NB + t] += base;
    }
}

// ---- partition pass 2: single-pass scatter.  Local-dst packed into src's
//      spare bits (src < 2^17): ONE aligned 8B store per edge. ----
__global__ void k_part_scatter(const int* __restrict__ src, const int* __restrict__ dst,
                               const float* __restrict__ ew, const int* __restrict__ wgbase,
                               int2* __restrict__ stage_sw) {
    __shared__ int cur[NB];
    __shared__ int base[NB];
    int tid = threadIdx.x;
    int w = blockIdx.x;
    for (int j = tid; j < NB; j += PH_T) { cur[j] = 0; base[j] = wgbase[w * NB + j]; }
    __syncthreads();
    int eb = w * PH_E;
    for (int k = 0; k < PH_E; k += PH_T) {
        int e = eb + k + tid;
        if (e < NE) {
            int d = dst[e], b = d >> 7;
            int off = atomicAdd(&cur[b], 1);
            stage_sw[base[b] + off] = make_int2(src[e] | ((d & 127) << 17),
                                               __float_as_int(ew[e]));
        }
    }
}

// ---- bucket finalize: row_ptr + dinv + px + in-window csr scatter ----
__global__ void k_bucket_fill(const int2* __restrict__ stage_sw,
                              const int* __restrict__ beb, const float* __restrict__ x,
                              int* __restrict__ row_ptr, int2* __restrict__ csr,
                              float* __restrict__ dinv, float* __restrict__ px) {
    __shared__ int cnt[128];
    __shared__ float deg[128];
    __shared__ int cur[128];
    __shared__ int sc[128];
    int b = blockIdx.x, tid = threadIdx.x;
    if (tid < 128) { cnt[tid] = 0; deg[tid] = 0.f; cur[tid] = 0; }
    __syncthreads();
    int eb0 = beb[b], eb1 = beb[b + 1];
    for (int i = eb0 + tid; i < eb1; i += 256) {
        int2 t = stage_sw[i];
        int j = (t.x >> 17) & 127;
        atomicAdd(&cnt[j], 1);
        atomicAdd(&deg[j], __int_as_float(t.y));
    }
    __syncthreads();
    if (tid < 128) sc[tid] = cnt[tid];
    __syncthreads();
    for (int off = 1; off < 128; off <<= 1) {
        int v = 0;
        if (tid < 128 && tid >= off) v = sc[tid - off];
        __syncthreads();
        if (tid < 128) sc[tid] += v;
        __syncthreads();
    }
    if (tid < 128) {
        int n = b * 128 + tid;
        int ex = tid ? sc[tid - 1] : 0;
        if (n <= NN) row_ptr[n] = eb0 + ex;   // n==NN writes the end sentinel (=NE)
        if (n < NN) {
            float di = rsqrtf(deg[tid] + 1.0f);
            dinv[n] = di;
            float4 a, bb;
            a.x = di * x[n * IND + 0]; a.y = di * x[n * IND + 1];
            a.z = di * x[n * IND + 2]; a.w = di * x[n * IND + 3];
            bb.x = di * x[n * IND + 4]; bb.y = 0.f; bb.z = 0.f; bb.w = 0.f;
            ((float4*)px)[n * 2 + 0] = a;
            ((float4*)px)[n * 2 + 1] = bb;
        }
    }
    __syncthreads();
    for (int i = eb0 + tid; i < eb1; i += 256) {
        int2 t = stage_sw[i];
        int j = (t.x >> 17) & 127;
        int ex = j ? sc[j - 1] : 0;
        int off = atomicAdd(&cur[j], 1);
        csr[eb0 + ex + off] = make_int2(t.x & 0x1FFFF, t.y);
    }
}

// ---- layer-1 aggregation on pre-scaled raw x ----
__global__ void k_gather_x(const float* __restrict__ px, const float* __restrict__ dinv,
                           const int* __restrict__ row_ptr, const int2* __restrict__ csr,
                           float* __restrict__ xa) {
    int gid = blockIdx.x * blockDim.x + threadIdx.x;  // NN*16 threads
    if (gid >= NN * 16) return;
    int n = gid >> 4, lane16 = gid & 15;
    const float4* p4 = (const float4*)px;
    int beg = row_ptr[n], end = row_ptr[n + 1];
    float4 a0 = make_float4(0.f, 0.f, 0.f, 0.f);
    float a4 = 0.f;
    int i = beg + lane16;
    if (i < end) {
        long long cur = __builtin_nontemporal_load((const long long*)&csr[i]);
        for (; i < end; i += 16) {
            int pi = (i + 16 < end) ? i + 16 : i;
            long long nxt = __builtin_nontemporal_load((const long long*)&csr[pi]);
            int   s = (int)(cur & 0xffffffffLL);
            float w = __int_as_float((int)(cur >> 32));
            float4 v0 = p4[s * 2 + 0];
            float  v4 = px[s * 8 + 4];
            a0.x += w * v0.x; a0.y += w * v0.y; a0.z += w * v0.z; a0.w += w * v0.w;
            a4 += w * v4;
            cur = nxt;
        }
    }
#pragma unroll
    for (int m = 8; m >= 1; m >>= 1) {
        a0.x += __shfl_xor(a0.x, m); a0.y += __shfl_xor(a0.y, m);
        a0.z += __shfl_xor(a0.z, m); a0.w += __shfl_xor(a0.w, m);
        a4 += __shfl_xor(a4, m);
    }
    if (lane16 == 0) {
        float di = dinv[n];
        float4 v0 = p4[n * 2 + 0];
        float  v4 = px[n * 8 + 4];
        float4 o0;
        o0.x = di * (a0.x + v0.x); o0.y = di * (a0.y + v0.y);
        o0.z = di * (a0.z + v0.z); o0.w = di * (a0.w + v0.w);
        ((float4*)xa)[n * 2 + 0] = o0;
        ((float4*)xa)[n * 2 + 1] = make_float4(di * (a4 + v4), 0.f, 0.f, 0.f);
    }
}

// ---- FUSED projection: h1 = relu(bn1(xa@W1+b1)) -> LDS -> h2 = dinv*(h1@W2)
//      -> fp16 tab.  Block = 16 nodes x 16 q-threads; 4 ch/thread, 4 chains. ----
__global__ void k_proj_fused(const float* __restrict__ xa, const float* __restrict__ W1,
                             const float* __restrict__ b1,
                             const float* __restrict__ g1, const float* __restrict__ be1,
                             const float* __restrict__ m1, const float* __restrict__ v1,
                             const float* __restrict__ W2, const float* __restrict__ dinv,
                             __half* __restrict__ tab) {
    __shared__ float4 W1s4[IND * 16];   // W1[k][4q..4q+3]
    __shared__ float4 Ws4[HID * 16];    // W2[k][4q..4q+3]
    __shared__ float4 h1s[16 * 16];     // 16 nodes x 64 ch
    {
        const float4* W14 = (const float4*)W1;
        for (int j = threadIdx.x; j < IND * 16; j += blockDim.x) W1s4[j] = W14[j];
        const float4* W24 = (const float4*)W2;
        for (int j = threadIdx.x; j < HID * 16; j += blockDim.x) Ws4[j] = W24[j];
    }
    __syncthreads();
    int tid = threadIdx.x;
    int nl = tid >> 4, q = tid & 15;
    int n = blockIdx.x * 16 + nl;          // grid is exactly NN*16/256 = 3125
    float4 v0 = ((const float4*)xa)[n * 2];
    float  v4 = xa[n * 8 + 4];
    int c0 = q * 4;
    float4 acc;
    {
        float4 w0 = W1s4[0 * 16 + q], w1 = W1s4[1 * 16 + q], w2 = W1s4[2 * 16 + q];
        float4 w3 = W1s4[3 * 16 + q], w4 = W1s4[4 * 16 + q];
        acc.x = b1[c0 + 0] + v0.x * w0.x + v0.y * w1.x + v0.z * w2.x + v0.w * w3.x + v4 * w4.x;
        acc.y = b1[c0 + 1] + v0.x * w0.y + v0.y * w1.y + v0.z * w2.y + v0.w * w3.y + v4 * w4.y;
        acc.z = b1[c0 + 2] + v0.x * w0.z + v0.y * w1.z + v0.z * w2.z + v0.w * w3.z + v4 * w4.z;
        acc.w = b1[c0 + 3] + v0.x * w0.w + v0.y * w1.w + v0.z * w2.w + v0.w * w3.w + v4 * w4.w;
    }
    float4 r;
    r.x = fmaxf((acc.x - m1[c0 + 0]) * rsqrtf(v1[c0 + 0] + EPSV) * g1[c0 + 0] + be1[c0 + 0], 0.f);
    r.y = fmaxf((acc.y - m1[c0 + 1]) * rsqrtf(v1[c0 + 1] + EPSV) * g1[c0 + 1] + be1[c0 + 1], 0.f);
    r.z = fmaxf((acc.z - m1[c0 + 2]) * rsqrtf(v1[c0 + 2] + EPSV) * g1[c0 + 2] + be1[c0 + 2], 0.f);
    r.w = fmaxf((acc.w - m1[c0 + 3]) * rsqrtf(v1[c0 + 3] + EPSV) * g1[c0 + 3] + be1[c0 + 3], 0.f);
    h1s[nl * 16 + q] = r;
    __syncthreads();
    float acc0 = 0.f, acc1 = 0.f, acc2 = 0.f, acc3 = 0.f;
#pragma unroll
    for (int k4 = 0; k4 < 16; k4++) {
        float4 av = h1s[nl * 16 + k4];       // broadcast across the 16 q-lanes
        float4 w0 = Ws4[(k4 * 4 + 0) * 16 + q];
        float4 w1 = Ws4[(k4 * 4 + 1) * 16 + q];
        float4 w2 = Ws4[(k4 * 4 + 2) * 16 + q];
        float4 w3 = Ws4[(k4 * 4 + 3) * 16 + q];
        acc0 += av.x * w0.x + av.y * w1.x + av.z * w2.x + av.w * w3.x;
        acc1 += av.x * w0.y + av.y * w1.y + av.z * w2.y + av.w * w3.y;
        acc2 += av.x * w0.z + av.y * w1.z + av.z * w2.z + av.w * w3.z;
        acc3 += av.x * w0.w + av.y * w1.w + av.z * w2.w + av.w * w3.w;
    }
    float di = dinv[n];
    __half2 h01 = __floats2half2_rn(di * acc0, di * acc1);
    __half2 h23 = __floats2half2_rn(di * acc2, di * acc3);
    uint2 packed;
    packed.x = *(const unsigned int*)&h01;
    packed.y = *(const unsigned int*)&h23;
    ((uint2*)tab)[n * 16 + q] = packed;
}

// ---- layer-2 gather (16 lanes/node, uint2/lane, 4-deep rolling edge unroll)
//      + bn2 + relu + LDS segmented pool reduction ----
__global__ void k_gather_pool(const __half* __restrict__ tab, const float* __restrict__ dinv,
                              const int* __restrict__ row_ptr, const int2* __restrict__ csr,
                              const float* __restrict__ bias,
                              const float* __restrict__ gamma, const float* __restrict__ beta,
                              const float* __restrict__ mean, const float* __restrict__ var,
                              const int* __restrict__ batch,
                              float* pool, float* cnt) {
    __shared__ float lds[16 * HID];
    __shared__ int gs[16];
    int tid = threadIdx.x;
    int gid = blockIdx.x * blockDim.x + tid;   // NN*16 threads exactly
    int n = gid >> 4, c4 = gid & 15;
    int nl = tid >> 4;
    if (tid < 16) gs[tid] = batch[blockIdx.x * 16 + tid];

    const uint2* hq = (const uint2*)tab;
    int beg = row_ptr[n], end = row_ptr[n + 1];

    uint2 sraw = hq[n * 16 + c4];
    float2 s01 = __half22float2(*(const __half2*)&sraw.x);
    float2 s23 = __half22float2(*(const __half2*)&sraw.y);
    float a0 = s01.x, a1 = s01.y, a2 = s23.x, a3 = s23.y;

    if (beg < end) {
        int last = end - 1;
        int i = beg;
        long long c0l = __builtin_nontemporal_load((const long long*)&csr[i]);
        long long c1l = __builtin_nontemporal_load((const long long*)&csr[(i + 1 < end) ? i + 1 : last]);
        long long c2l = __builtin_nontemporal_load((const long long*)&csr[(i + 2 < end) ? i + 2 : last]);
        long long c3l = __builtin_nontemporal_load((const long long*)&csr[(i + 3 < end) ? i + 3 : last]);
        for (; i + 4 <= end; i += 4) {
            long long p0 = __builtin_nontemporal_load((const long long*)&csr[(i + 4 < end) ? i + 4 : last]);
            long long p1 = __builtin_nontemporal_load((const long long*)&csr[(i + 5 < end) ? i + 5 : last]);
            long long p2 = __builtin_nontemporal_load((const long long*)&csr[(i + 6 < end) ? i + 6 : last]);
            long long p3 = __builtin_nontemporal_load((const long long*)&csr[(i + 7 < end) ? i + 7 : last]);
            int   s0 = (int)(c0l & 0xffffffffLL);
            int   s1 = (int)(c1l & 0xffffffffLL);
            int   s2 = (int)(c2l & 0xffffffffLL);
            int   s3 = (int)(c3l & 0xffffffffLL);
            float w0 = __int_as_float((int)(c0l >> 32));
            float w1 = __int_as_float((int)(c1l >> 32));
            float w2 = __int_as_float((int)(c2l >> 32));
            float w3 = __int_as_float((int)(c3l >> 32));
            uint2 r0 = hq[s0 * 16 + c4];            // four independent loads
            uint2 r1 = hq[s1 * 16 + c4];
            uint2 r2 = hq[s2 * 16 + c4];
            uint2 r3 = hq[s3 * 16 + c4];
            float2 f;
            f = __half22float2(*(const __half2*)&r0.x); a0 += w0 * f.x; a1 += w0 * f.y;
            f = __half22float2(*(const __half2*)&r0.y); a2 += w0 * f.x; a3 += w0 * f.y;
            f = __half22float2(*(const __half2*)&r1.x); a0 += w1 * f.x; a1 += w1 * f.y;
            f = __half22float2(*(const __half2*)&r1.y); a2 += w1 * f.x; a3 += w1 * f.y;
            f = __half22float2(*(const __half2*)&r2.x); a0 += w2 * f.x; a1 += w2 * f.y;
            f = __half22float2(*(const __half2*)&r2.y); a2 += w2 * f.x; a3 += w2 * f.y;
            f = __half22float2(*(const __half2*)&r3.x); a0 += w3 * f.x; a1 += w3 * f.y;
            f = __half22float2(*(const __half2*)&r3.y); a2 += w3 * f.x; a3 += w3 * f.y;
            c0l = p0; c1l = p1; c2l = p2; c3l = p3;
        }
        int rem = end - i;                           // 0..3 entries left in c0l..c2l
        if (rem > 0) {
            int   s0 = (int)(c0l & 0xffffffffLL);
            float w0 = __int_as_float((int)(c0l >> 32));
            uint2 r0 = hq[s0 * 16 + c4];
            float2 f;
            f = __half22float2(*(const __half2*)&r0.x); a0 += w0 * f.x; a1 += w0 * f.y;
            f = __half22float2(*(const __half2*)&r0.y); a2 += w0 * f.x; a3 += w0 * f.y;
        }
        if (rem > 1) {
            int   s1 = (int)(c1l & 0xffffffffLL);
            float w1 = __int_as_float((int)(c1l >> 32));
            uint2 r1 = hq[s1 * 16 + c4];
            float2 f;
            f = __half22float2(*(const __half2*)&r1.x); a0 += w1 * f.x; a1 += w1 * f.y;
            f = __half22float2(*(const __half2*)&r1.y); a2 += w1 * f.x; a3 += w1 * f.y;
        }
        if (rem > 2) {
            int   s2 = (int)(c2l & 0xffffffffLL);
            float w2 = __int_as_float((int)(c2l >> 32));
            uint2 r2 = hq[s2 * 16 + c4];
            float2 f;
            f = __half22float2(*(const __half2*)&r2.x); a0 += w2 * f.x; a1 += w2 * f.y;
            f = __half22float2(*(const __half2*)&r2.y); a2 += w2 * f.x; a3 += w2 * f.y;
        }
    }

    float di = dinv[n];
    int c0 = c4 * 4;
    float4 r;
    {
        float vv0 = di * a0 + bias[c0 + 0];
        float vv1 = di * a1 + bias[c0 + 1];
        float vv2 = di * a2 + bias[c0 + 2];
        float vv3 = di * a3 + bias[c0 + 3];
        r.x = fmaxf((vv0 - mean[c0 + 0]) * rsqrtf(var[c0 + 0] + EPSV) * gamma[c0 + 0] + beta[c0 + 0], 0.f);
        r.y = fmaxf((vv1 - mean[c0 + 1]) * rsqrtf(var[c0 + 1] + EPSV) * gamma[c0 + 1] + beta[c0 + 1], 0.f);
        r.z = fmaxf((vv2 - mean[c0 + 2]) * rsqrtf(var[c0 + 2] + EPSV) * gamma[c0 + 2] + beta[c0 + 2], 0.f);
        r.w = fmaxf((vv3 - mean[c0 + 3]) * rsqrtf(var[c0 + 3] + EPSV) * gamma[c0 + 3] + beta[c0 + 3], 0.f);
    }
    ((float4*)lds)[nl * 16 + c4] = r;
    __syncthreads();

    if (tid < HID) {
        int c = tid;
        float run = lds[0 * HID + c];
        int gprev = gs[0];
#pragma unroll
        for (int node = 1; node < 16; node++) {
            int g = gs[node];
            float v = lds[node * HID + c];
            if (g != gprev) { atomicAdd(&pool[gprev * HID + c], run); run = v; gprev = g; }
            else run += v;
        }
        atomicAdd(&pool[gprev * HID + c], run);
    } else if (tid == HID) {
        int run = 1, gprev = gs[0];
        for (int node = 1; node < 16; node++) {
            int g = gs[node];
            if (g != gprev) { atomicAdd(&cnt[gprev], (float)run); run = 0; gprev = g; }
            run++;
        }
        atomicAdd(&cnt[gprev], (float)run);
    }
}

// ---- final MLP: one wave per graph ----
__global__ void k_mlp(const float* __restrict__ pool_sums, const float* __restrict__ cnt,
                      const float* __restrict__ l1W, const float* __restrict__ l1b,
                      const float* __restrict__ l2W, const float* __restrict__ l2b,
                      float* __restrict__ outp) {
    int g = blockIdx.x;
    int lane = threadIdx.x;           // 64
    int j = lane & 31, kh = lane >> 5;
    const float* pg = &pool_sums[g * HID];
    float z = 0.f;
#pragma unroll 8
    for (int k = kh * 32; k < kh * 32 + 32; k++)
        z += pg[k] * l1W[k * (HID / 2) + j];
    z += __shfl_xor(z, 32);           // join k-halves
    float inv = 1.0f / fmaxf(cnt[g], 1.0f);
    float acc = (kh == 0) ? fmaxf(z * inv + l1b[j], 0.f) * l2W[j] : 0.f;
#pragma unroll
    for (int m = 16; m >= 1; m >>= 1) acc += __shfl_xor(acc, m);
    if (lane == 0) outp[g] = acc + l2b[0];
}

extern "C" void kernel_launch(void* const* d_in, const int* in_sizes, int n_in,
                              void* d_out, int out_size, void* d_ws, size_t ws_size,
                              hipStream_t stream) {
    const float* x   = (const float*)d_in[0];
    const int*   ei  = (const int*)d_in[1];
    const float* ew  = (const float*)d_in[2];
    const int*   bat = (const int*)d_in[3];
    const float* W1  = (const float*)d_in[4];
    const float* b1  = (const float*)d_in[5];
    const float* W2  = (const float*)d_in[6];
    const float* b2  = (const float*)d_in[7];
    const float* g1  = (const float*)d_in[8];
    const float* be1 = (const float*)d_in[9];
    const float* m1  = (const float*)d_in[10];
    const float* v1  = (const float*)d_in[11];
    const float* g2  = (const float*)d_in[12];
    const float* be2 = (const float*)d_in[13];
    const float* m2  = (const float*)d_in[14];
    const float* v2  = (const float*)d_in[15];
    const float* l1W = (const float*)d_in[16];
    const float* l1b = (const float*)d_in[17];
    const float* l2W = (const float*)d_in[18];
    const float* l2b = (const float*)d_in[19];
    float* out = (float*)d_out;

    const int* src = ei;
    const int* dst = ei + NE;

    // ---- workspace layout (4-byte units); no memset — every buffer is either
    //      fully written each call or zeroed inside k_part_hist ----
    float* f = (float*)d_ws;
    float* pool      = f + 0;                    // 8192 (zeroed by k_part_hist)
    float* cnt       = f + 8192;                 // 128  (zeroed by k_part_hist)
    int*   h_wg      = (int*)(f + 8320);         // 391*391 = 152881 (fully written)
    int*   wgbase    = (int*)(f + 161201);       // 152881 (fully written)
    int*   beb       = (int*)(f + 314082);       // 392 (fully written)
    int*   row_ptr   = (int*)(f + 314474);       // 50001 (fully written)
    int2*  csr       = (int2*)(f + 364476);      // 800000 int2 (8B aligned) -> 1964476
    float* dinv      = f + 1964476;              // 50000
    float* px        = f + 2014476;              // NN*8 -> 2414476
    float* xa        = f + 2414476;              // NN*8 -> 2814476
    int2*  stage_sw  = (int2*)(f + 2814476);     // 800000 int2 -> 4414476
    __half* tab      = (__half*)(f + 4414476);   // NN*HID fp16 -> 6014476 (24.1 MB)

    const int BLK = 256;
    const int gN16 = (NN * 16 + BLK - 1) / BLK;   // 3125 blocks (exact)

    // CSR build: bucket-partitioned, 391-WG high-occupancy partition passes
    k_part_hist<<<PH_WG, PH_T, 0, stream>>>(dst, h_wg, pool);
    k_bscan<<<1, 512, 0, stream>>>(h_wg, wgbase, beb);
    k_part_scatter<<<PH_WG, PH_T, 0, stream>>>(src, dst, ew, wgbase, stage_sw);
    k_bucket_fill<<<NB, BLK, 0, stream>>>(stage_sw, beb, x, row_ptr, csr, dinv, px);

    // layer 1 aggregation, then FUSED projection (gemm1+bn1+relu+gemm2 -> tab)
    k_gather_x<<<gN16, BLK, 0, stream>>>(px, dinv, row_ptr, csr, xa);
    k_proj_fused<<<gN16, BLK, 0, stream>>>(xa, W1, b1, g1, be1, m1, v1, W2, dinv, tab);

    // layer 2 gather + bn2 + relu + LDS pool
    k_gather_pool<<<gN16, BLK, 0, stream>>>(tab, dinv, row_ptr, csr, b2,
                                            g2, be2, m2, v2, bat, pool, cnt);

    // MLP head: one wave per graph
    k_mlp<<<NG, 64, 0, stream>>>(pool, cnt, l1W, l1b, l2W, l2b, out);
}

// Round 20
// 106.877 us; speedup vs baseline: 1.7767x; 1.7767x over previous
//
#include <hip/hip_runtime.h>
#include <hip/hip_fp16.h>

#define NN 50000
#define NE 800000
#define NG 128
#define IND 5
#define HID 64
#define EPSV 1e-5f

#define NB 391          // buckets of 128 nodes: 391*128 = 50048 >= 50001
#define PH_T 256        // partition wg size
#define PH_E 2048       // edges per partition wg
#define PH_WG ((NE + PH_E - 1) / PH_E)   // 391 wgs
#define PH_PAD 392      // padded stride for transposed slice arrays

// ---- partition pass 1: per-WG bucket histogram slices, TRANSPOSED layout
//      h_wgT[bucket][wg] (contiguous per bucket for the parallel column scan);
//      also zeroes pool/cnt ----
__global__ void k_part_hist(const int* __restrict__ dst, int* __restrict__ h_wgT,
                            float* __restrict__ pool_zero) {
    __shared__ int h[NB];
    int tid = threadIdx.x;
    int zgid = blockIdx.x * PH_T + tid;
    if (zgid < NG * HID + NG) pool_zero[zgid] = 0.f;
    for (int j = tid; j < NB; j += PH_T) h[j] = 0;
    __syncthreads();
    int base = blockIdx.x * PH_E;
    for (int k = 0; k < PH_E; k += PH_T) {
        int e = base + k + tid;
        if (e < NE) atomicAdd(&h[dst[e] >> 7], 1);
    }
    __syncthreads();
    for (int j = tid; j < NB; j += PH_T) h_wgT[j * PH_PAD + blockIdx.x] = h[j];
}

// ---- parallel column scan: one WAVE per bucket — exclusive prefix over the
//      391 per-WG counts (7 shfl-scan chunks), writes wgbaseT + bucket total.
//      (Replaces the 94us single-block serial bscan of R19.) ----
__global__ void k_col_scan(const int* __restrict__ h_wgT, int* __restrict__ wgbaseT,
                           int* __restrict__ tot) {
    int j = blockIdx.x;               // bucket
    int lane = threadIdx.x;           // 64
    const int* col = &h_wgT[j * PH_PAD];
    int* ob = &wgbaseT[j * PH_PAD];
    int carry = 0;
    for (int w0 = 0; w0 < PH_WG; w0 += 64) {
        int w = w0 + lane;
        int orig = (w < PH_WG) ? col[w] : 0;
        int v = orig;
#pragma unroll
        for (int off = 1; off < 64; off <<= 1) {
            int o = __shfl_up(v, off);
            if (lane >= off) v += o;
        }
        if (w < PH_WG) ob[w] = carry + v - orig;   // exclusive
        carry += __shfl(v, 63);
    }
    if (lane == 0) tot[j] = carry;
}

// ---- tiny scan of 391 bucket totals -> beb[0..NB] ----
__global__ void k_tot_scan(const int* __restrict__ tot, int* __restrict__ beb) {
    __shared__ int sm[512];
    int t = threadIdx.x;
    sm[t] = (t < NB) ? tot[t] : 0;
    __syncthreads();
    for (int off = 1; off < 512; off <<= 1) {
        int v = (t >= off) ? sm[t - off] : 0;
        __syncthreads();
        sm[t] += v;
        __syncthreads();
    }
    if (t <= NB) beb[t] = t ? sm[t - 1] : 0;
}

// ---- partition pass 2: single-pass scatter; base = wgbaseT[j][w] + beb[j].
//      Local-dst packed into src's spare bits: ONE aligned 8B store/edge. ----
__global__ void k_part_scatter(const int* __restrict__ src, const int* __restrict__ dst,
                               const float* __restrict__ ew,
                               const int* __restrict__ wgbaseT, const int* __restrict__ beb,
                               int2* __restrict__ stage_sw) {
    __shared__ int cur[NB];
    __shared__ int base[NB];
    int tid = threadIdx.x;
    int w = blockIdx.x;
    for (int j = tid; j < NB; j += PH_T) {
        cur[j] = 0;
        base[j] = wgbaseT[j * PH_PAD + w] + beb[j];
    }
    __syncthreads();
    int eb = w * PH_E;
    for (int k = 0; k < PH_E; k += PH_T) {
        int e = eb + k + tid;
        if (e < NE) {
            int d = dst[e], b = d >> 7;
            int off = atomicAdd(&cur[b], 1);
            stage_sw[base[b] + off] = make_int2(src[e] | ((d & 127) << 17),
                                               __float_as_int(ew[e]));
        }
    }
}

// ---- bucket finalize: row_ptr + dinv + px + in-window csr scatter ----
__global__ void k_bucket_fill(const int2* __restrict__ stage_sw,
                              const int* __restrict__ beb, const float* __restrict__ x,
                              int* __restrict__ row_ptr, int2* __restrict__ csr,
                              float* __restrict__ dinv, float* __restrict__ px) {
    __shared__ int cnt[128];
    __shared__ float deg[128];
    __shared__ int cur[128];
    __shared__ int sc[128];
    int b = blockIdx.x, tid = threadIdx.x;
    if (tid < 128) { cnt[tid] = 0; deg[tid] = 0.f; cur[tid] = 0; }
    __syncthreads();
    int eb0 = beb[b], eb1 = beb[b + 1];
    for (int i = eb0 + tid; i < eb1; i += 256) {
        int2 t = stage_sw[i];
        int j = (t.x >> 17) & 127;
        atomicAdd(&cnt[j], 1);
        atomicAdd(&deg[j], __int_as_float(t.y));
    }
    __syncthreads();
    if (tid < 128) sc[tid] = cnt[tid];
    __syncthreads();
    for (int off = 1; off < 128; off <<= 1) {
        int v = 0;
        if (tid < 128 && tid >= off) v = sc[tid - off];
        __syncthreads();
        if (tid < 128) sc[tid] += v;
        __syncthreads();
    }
    if (tid < 128) {
        int n = b * 128 + tid;
        int ex = tid ? sc[tid - 1] : 0;
        if (n <= NN) row_ptr[n] = eb0 + ex;   // n==NN writes the end sentinel (=NE)
        if (n < NN) {
            float di = rsqrtf(deg[tid] + 1.0f);
            dinv[n] = di;
            float4 a, bb;
            a.x = di * x[n * IND + 0]; a.y = di * x[n * IND + 1];
            a.z = di * x[n * IND + 2]; a.w = di * x[n * IND + 3];
            bb.x = di * x[n * IND + 4]; bb.y = 0.f; bb.z = 0.f; bb.w = 0.f;
            ((float4*)px)[n * 2 + 0] = a;
            ((float4*)px)[n * 2 + 1] = bb;
        }
    }
    __syncthreads();
    for (int i = eb0 + tid; i < eb1; i += 256) {
        int2 t = stage_sw[i];
        int j = (t.x >> 17) & 127;
        int ex = j ? sc[j - 1] : 0;
        int off = atomicAdd(&cur[j], 1);
        csr[eb0 + ex + off] = make_int2(t.x & 0x1FFFF, t.y);
    }
}

// ---- layer-1 aggregation on pre-scaled raw x ----
__global__ void k_gather_x(const float* __restrict__ px, const float* __restrict__ dinv,
                           const int* __restrict__ row_ptr, const int2* __restrict__ csr,
                           float* __restrict__ xa) {
    int gid = blockIdx.x * blockDim.x + threadIdx.x;  // NN*16 threads
    if (gid >= NN * 16) return;
    int n = gid >> 4, lane16 = gid & 15;
    const float4* p4 = (const float4*)px;
    int beg = row_ptr[n], end = row_ptr[n + 1];
    float4 a0 = make_float4(0.f, 0.f, 0.f, 0.f);
    float a4 = 0.f;
    int i = beg + lane16;
    if (i < end) {
        long long cur = __builtin_nontemporal_load((const long long*)&csr[i]);
        for (; i < end; i += 16) {
            int pi = (i + 16 < end) ? i + 16 : i;
            long long nxt = __builtin_nontemporal_load((const long long*)&csr[pi]);
            int   s = (int)(cur & 0xffffffffLL);
            float w = __int_as_float((int)(cur >> 32));
            float4 v0 = p4[s * 2 + 0];
            float  v4 = px[s * 8 + 4];
            a0.x += w * v0.x; a0.y += w * v0.y; a0.z += w * v0.z; a0.w += w * v0.w;
            a4 += w * v4;
            cur = nxt;
        }
    }
#pragma unroll
    for (int m = 8; m >= 1; m >>= 1) {
        a0.x += __shfl_xor(a0.x, m); a0.y += __shfl_xor(a0.y, m);
        a0.z += __shfl_xor(a0.z, m); a0.w += __shfl_xor(a0.w, m);
        a4 += __shfl_xor(a4, m);
    }
    if (lane16 == 0) {
        float di = dinv[n];
        float4 v0 = p4[n * 2 + 0];
        float  v4 = px[n * 8 + 4];
        float4 o0;
        o0.x = di * (a0.x + v0.x); o0.y = di * (a0.y + v0.y);
        o0.z = di * (a0.z + v0.z); o0.w = di * (a0.w + v0.w);
        ((float4*)xa)[n * 2 + 0] = o0;
        ((float4*)xa)[n * 2 + 1] = make_float4(di * (a4 + v4), 0.f, 0.f, 0.f);
    }
}

// ---- FUSED projection: h1 = relu(bn1(xa@W1+b1)) -> LDS -> h2 = dinv*(h1@W2)
//      -> fp16 tab.  Block = 16 nodes x 16 q-threads; 4 ch/thread, 4 chains. ----
__global__ void k_proj_fused(const float* __restrict__ xa, const float* __restrict__ W1,
                             const float* __restrict__ b1,
                             const float* __restrict__ g1, const float* __restrict__ be1,
                             const float* __restrict__ m1, const float* __restrict__ v1,
                             const float* __restrict__ W2, const float* __restrict__ dinv,
                             __half* __restrict__ tab) {
    __shared__ float4 W1s4[IND * 16];   // W1[k][4q..4q+3]
    __shared__ float4 Ws4[HID * 16];    // W2[k][4q..4q+3]
    __shared__ float4 h1s[16 * 16];     // 16 nodes x 64 ch
    {
        const float4* W14 = (const float4*)W1;
        for (int j = threadIdx.x; j < IND * 16; j += blockDim.x) W1s4[j] = W14[j];
        const float4* W24 = (const float4*)W2;
        for (int j = threadIdx.x; j < HID * 16; j += blockDim.x) Ws4[j] = W24[j];
    }
    __syncthreads();
    int tid = threadIdx.x;
    int nl = tid >> 4, q = tid & 15;
    int n = blockIdx.x * 16 + nl;          // grid is exactly NN*16/256 = 3125
    float4 v0 = ((const float4*)xa)[n * 2];
    float  v4 = xa[n * 8 + 4];
    int c0 = q * 4;
    float4 acc;
    {
        float4 w0 = W1s4[0 * 16 + q], w1 = W1s4[1 * 16 + q], w2 = W1s4[2 * 16 + q];
        float4 w3 = W1s4[3 * 16 + q], w4 = W1s4[4 * 16 + q];
        acc.x = b1[c0 + 0] + v0.x * w0.x + v0.y * w1.x + v0.z * w2.x + v0.w * w3.x + v4 * w4.x;
        acc.y = b1[c0 + 1] + v0.x * w0.y + v0.y * w1.y + v0.z * w2.y + v0.w * w3.y + v4 * w4.y;
        acc.z = b1[c0 + 2] + v0.x * w0.z + v0.y * w1.z + v0.z * w2.z + v0.w * w3.z + v4 * w4.z;
        acc.w = b1[c0 + 3] + v0.x * w0.w + v0.y * w1.w + v0.z * w2.w + v0.w * w3.w + v4 * w4.w;
    }
    float4 r;
    r.x = fmaxf((acc.x - m1[c0 + 0]) * rsqrtf(v1[c0 + 0] + EPSV) * g1[c0 + 0] + be1[c0 + 0], 0.f);
    r.y = fmaxf((acc.y - m1[c0 + 1]) * rsqrtf(v1[c0 + 1] + EPSV) * g1[c0 + 1] + be1[c0 + 1], 0.f);
    r.z = fmaxf((acc.z - m1[c0 + 2]) * rsqrtf(v1[c0 + 2] + EPSV) * g1[c0 + 2] + be1[c0 + 2], 0.f);
    r.w = fmaxf((acc.w - m1[c0 + 3]) * rsqrtf(v1[c0 + 3] + EPSV) * g1[c0 + 3] + be1[c0 + 3], 0.f);
    h1s[nl * 16 + q] = r;
    __syncthreads();
    float acc0 = 0.f, acc1 = 0.f, acc2 = 0.f, acc3 = 0.f;
#pragma unroll
    for (int k4 = 0; k4 < 16; k4++) {
        float4 av = h1s[nl * 16 + k4];       // broadcast across the 16 q-lanes
        float4 w0 = Ws4[(k4 * 4 + 0) * 16 + q];
        float4 w1 = Ws4[(k4 * 4 + 1) * 16 + q];
        float4 w2 = Ws4[(k4 * 4 + 2) * 16 + q];
        float4 w3 = Ws4[(k4 * 4 + 3) * 16 + q];
        acc0 += av.x * w0.x + av.y * w1.x + av.z * w2.x + av.w * w3.x;
        acc1 += av.x * w0.y + av.y * w1.y + av.z * w2.y + av.w * w3.y;
        acc2 += av.x * w0.z + av.y * w1.z + av.z * w2.z + av.w * w3.z;
        acc3 += av.x * w0.w + av.y * w1.w + av.z * w2.w + av.w * w3.w;
    }
    float di = dinv[n];
    __half2 h01 = __floats2half2_rn(di * acc0, di * acc1);
    __half2 h23 = __floats2half2_rn(di * acc2, di * acc3);
    uint2 packed;
    packed.x = *(const unsigned int*)&h01;
    packed.y = *(const unsigned int*)&h23;
    ((uint2*)tab)[n * 16 + q] = packed;
}

// ---- layer-2 gather (16 lanes/node, uint2/lane, 4-deep rolling edge unroll)
//      + bn2 + relu + LDS segmented pool reduction ----
__global__ void k_gather_pool(const __half* __restrict__ tab, const float* __restrict__ dinv,
                              const int* __restrict__ row_ptr, const int2* __restrict__ csr,
                              const float* __restrict__ bias,
                              const float* __restrict__ gamma, const float* __restrict__ beta,
                              const float* __restrict__ mean, const float* __restrict__ var,
                              const int* __restrict__ batch,
                              float* pool, float* cnt) {
    __shared__ float lds[16 * HID];
    __shared__ int gs[16];
    int tid = threadIdx.x;
    int gid = blockIdx.x * blockDim.x + tid;   // NN*16 threads exactly
    int n = gid >> 4, c4 = gid & 15;
    int nl = tid >> 4;
    if (tid < 16) gs[tid] = batch[blockIdx.x * 16 + tid];

    const uint2* hq = (const uint2*)tab;
    int beg = row_ptr[n], end = row_ptr[n + 1];

    uint2 sraw = hq[n * 16 + c4];
    float2 s01 = __half22float2(*(const __half2*)&sraw.x);
    float2 s23 = __half22float2(*(const __half2*)&sraw.y);
    float a0 = s01.x, a1 = s01.y, a2 = s23.x, a3 = s23.y;

    if (beg < end) {
        int last = end - 1;
        int i = beg;
        long long c0l = __builtin_nontemporal_load((const long long*)&csr[i]);
        long long c1l = __builtin_nontemporal_load((const long long*)&csr[(i + 1 < end) ? i + 1 : last]);
        long long c2l = __builtin_nontemporal_load((const long long*)&csr[(i + 2 < end) ? i + 2 : last]);
        long long c3l = __builtin_nontemporal_load((const long long*)&csr[(i + 3 < end) ? i + 3 : last]);
        for (; i + 4 <= end; i += 4) {
            long long p0 = __builtin_nontemporal_load((const long long*)&csr[(i + 4 < end) ? i + 4 : last]);
            long long p1 = __builtin_nontemporal_load((const long long*)&csr[(i + 5 < end) ? i + 5 : last]);
            long long p2 = __builtin_nontemporal_load((const long long*)&csr[(i + 6 < end) ? i + 6 : last]);
            long long p3 = __builtin_nontemporal_load((const long long*)&csr[(i + 7 < end) ? i + 7 : last]);
            int   s0 = (int)(c0l & 0xffffffffLL);
            int   s1 = (int)(c1l & 0xffffffffLL);
            int   s2 = (int)(c2l & 0xffffffffLL);
            int   s3 = (int)(c3l & 0xffffffffLL);
            float w0 = __int_as_float((int)(c0l >> 32));
            float w1 = __int_as_float((int)(c1l >> 32));
            float w2 = __int_as_float((int)(c2l >> 32));
            float w3 = __int_as_float((int)(c3l >> 32));
            uint2 r0 = hq[s0 * 16 + c4];            // four independent loads
            uint2 r1 = hq[s1 * 16 + c4];
            uint2 r2 = hq[s2 * 16 + c4];
            uint2 r3 = hq[s3 * 16 + c4];
            float2 f;
            f = __half22float2(*(const __half2*)&r0.x); a0 += w0 * f.x; a1 += w0 * f.y;
            f = __half22float2(*(const __half2*)&r0.y); a2 += w0 * f.x; a3 += w0 * f.y;
            f = __half22float2(*(const __half2*)&r1.x); a0 += w1 * f.x; a1 += w1 * f.y;
            f = __half22float2(*(const __half2*)&r1.y); a2 += w1 * f.x; a3 += w1 * f.y;
            f = __half22float2(*(const __half2*)&r2.x); a0 += w2 * f.x; a1 += w2 * f.y;
            f = __half22float2(*(const __half2*)&r2.y); a2 += w2 * f.x; a3 += w2 * f.y;
            f = __half22float2(*(const __half2*)&r3.x); a0 += w3 * f.x; a1 += w3 * f.y;
            f = __half22float2(*(const __half2*)&r3.y); a2 += w3 * f.x; a3 += w3 * f.y;
            c0l = p0; c1l = p1; c2l = p2; c3l = p3;
        }
        int rem = end - i;                           // 0..3 entries left in c0l..c2l
        if (rem > 0) {
            int   s0 = (int)(c0l & 0xffffffffLL);
            float w0 = __int_as_float((int)(c0l >> 32));
            uint2 r0 = hq[s0 * 16 + c4];
            float2 f;
            f = __half22float2(*(const __half2*)&r0.x); a0 += w0 * f.x; a1 += w0 * f.y;
            f = __half22float2(*(const __half2*)&r0.y); a2 += w0 * f.x; a3 += w0 * f.y;
        }
        if (rem > 1) {
            int   s1 = (int)(c1l & 0xffffffffLL);
            float w1 = __int_as_float((int)(c1l >> 32));
            uint2 r1 = hq[s1 * 16 + c4];
            float2 f;
            f = __half22float2(*(const __half2*)&r1.x); a0 += w1 * f.x; a1 += w1 * f.y;
            f = __half22float2(*(const __half2*)&r1.y); a2 += w1 * f.x; a3 += w1 * f.y;
        }
        if (rem > 2) {
            int   s2 = (int)(c2l & 0xffffffffLL);
            float w2 = __int_as_float((int)(c2l >> 32));
            uint2 r2 = hq[s2 * 16 + c4];
            float2 f;
            f = __half22float2(*(const __half2*)&r2.x); a0 += w2 * f.x; a1 += w2 * f.y;
            f = __half22float2(*(const __half2*)&r2.y); a2 += w2 * f.x; a3 += w2 * f.y;
        }
    }

    float di = dinv[n];
    int c0 = c4 * 4;
    float4 r;
    {
        float vv0 = di * a0 + bias[c0 + 0];
        float vv1 = di * a1 + bias[c0 + 1];
        float vv2 = di * a2 + bias[c0 + 2];
        float vv3 = di * a3 + bias[c0 + 3];
        r.x = fmaxf((vv0 - mean[c0 + 0]) * rsqrtf(var[c0 + 0] + EPSV) * gamma[c0 + 0] + beta[c0 + 0], 0.f);
        r.y = fmaxf((vv1 - mean[c0 + 1]) * rsqrtf(var[c0 + 1] + EPSV) * gamma[c0 + 1] + beta[c0 + 1], 0.f);
        r.z = fmaxf((vv2 - mean[c0 + 2]) * rsqrtf(var[c0 + 2] + EPSV) * gamma[c0 + 2] + beta[c0 + 2], 0.f);
        r.w = fmaxf((vv3 - mean[c0 + 3]) * rsqrtf(var[c0 + 3] + EPSV) * gamma[c0 + 3] + beta[c0 + 3], 0.f);
    }
    ((float4*)lds)[nl * 16 + c4] = r;
    __syncthreads();

    if (tid < HID) {
        int c = tid;
        float run = lds[0 * HID + c];
        int gprev = gs[0];
#pragma unroll
        for (int node = 1; node < 16; node++) {
            int g = gs[node];
            float v = lds[node * HID + c];
            if (g != gprev) { atomicAdd(&pool[gprev * HID + c], run); run = v; gprev = g; }
            else run += v;
        }
        atomicAdd(&pool[gprev * HID + c], run);
    } else if (tid == HID) {
        int run = 1, gprev = gs[0];
        for (int node = 1; node < 16; node++) {
            int g = gs[node];
            if (g != gprev) { atomicAdd(&cnt[gprev], (float)run); run = 0; gprev = g; }
            run++;
        }
        atomicAdd(&cnt[gprev], (float)run);
    }
}

// ---- final MLP: one wave per graph ----
__global__ void k_mlp(const float* __restrict__ pool_sums, const float* __restrict__ cnt,
                      const float* __restrict__ l1W, const float* __restrict__ l1b,
                      const float* __restrict__ l2W, const float* __restrict__ l2b,
                      float* __restrict__ outp) {
    int g = blockIdx.x;
    int lane = threadIdx.x;           // 64
    int j = lane & 31, kh = lane >> 5;
    const float* pg = &pool_sums[g * HID];
    float z = 0.f;
#pragma unroll 8
    for (int k = kh * 32; k < kh * 32 + 32; k++)
        z += pg[k] * l1W[k * (HID / 2) + j];
    z += __shfl_xor(z, 32);           // join k-halves
    float inv = 1.0f / fmaxf(cnt[g], 1.0f);
    float acc = (kh == 0) ? fmaxf(z * inv + l1b[j], 0.f) * l2W[j] : 0.f;
#pragma unroll
    for (int m = 16; m >= 1; m >>= 1) acc += __shfl_xor(acc, m);
    if (lane == 0) outp[g] = acc + l2b[0];
}

extern "C" void kernel_launch(void* const* d_in, const int* in_sizes, int n_in,
                              void* d_out, int out_size, void* d_ws, size_t ws_size,
                              hipStream_t stream) {
    const float* x   = (const float*)d_in[0];
    const int*   ei  = (const int*)d_in[1];
    const float* ew  = (const float*)d_in[2];
    const int*   bat = (const int*)d_in[3];
    const float* W1  = (const float*)d_in[4];
    const float* b1  = (const float*)d_in[5];
    const float* W2  = (const float*)d_in[6];
    const float* b2  = (const float*)d_in[7];
    const float* g1  = (const float*)d_in[8];
    const float* be1 = (const float*)d_in[9];
    const float* m1  = (const float*)d_in[10];
    const float* v1  = (const float*)d_in[11];
    const float* g2  = (const float*)d_in[12];
    const float* be2 = (const float*)d_in[13];
    const float* m2  = (const float*)d_in[14];
    const float* v2  = (const float*)d_in[15];
    const float* l1W = (const float*)d_in[16];
    const float* l1b = (const float*)d_in[17];
    const float* l2W = (const float*)d_in[18];
    const float* l2b = (const float*)d_in[19];
    float* out = (float*)d_out;

    const int* src = ei;
    const int* dst = ei + NE;

    // ---- workspace layout (4-byte units); no memset — every buffer is either
    //      fully written each call or zeroed inside k_part_hist ----
    float* f = (float*)d_ws;
    float* pool      = f + 0;                    // 8192 (zeroed by k_part_hist)
    float* cnt       = f + 8192;                 // 128  (zeroed by k_part_hist)
    int*   h_wgT     = (int*)(f + 8320);         // NB*PH_PAD = 153272 (fully written)
    int*   wgbaseT   = (int*)(f + 161592);       // 153272 (fully written)
    int*   tot       = (int*)(f + 314864);       // 391 (fully written)
    int*   beb       = (int*)(f + 315255);       // 392 (fully written)
    int*   row_ptr   = (int*)(f + 315647);       // 50001 (fully written)
    int2*  csr       = (int2*)(f + 365650);      // 800000 int2 (8B aligned) -> 1965650
    float* dinv      = f + 1965650;              // 50000
    float* px        = f + 2015650;              // NN*8 -> 2415650
    float* xa        = f + 2415650;              // NN*8 -> 2815650
    int2*  stage_sw  = (int2*)(f + 2815650);     // 800000 int2 -> 4415650
    __half* tab      = (__half*)(f + 4415650);   // NN*HID fp16 -> 6015650 (24.1 MB)

    const int BLK = 256;
    const int gN16 = (NN * 16 + BLK - 1) / BLK;   // 3125 blocks (exact)

    // CSR build: bucket-partitioned, 391-WG passes, PARALLEL column scan
    k_part_hist<<<PH_WG, PH_T, 0, stream>>>(dst, h_wgT, pool);
    k_col_scan<<<NB, 64, 0, stream>>>(h_wgT, wgbaseT, tot);
    k_tot_scan<<<1, 512, 0, stream>>>(tot, beb);
    k_part_scatter<<<PH_WG, PH_T, 0, stream>>>(src, dst, ew, wgbaseT, beb, stage_sw);
    k_bucket_fill<<<NB, BLK, 0, stream>>>(stage_sw, beb, x, row_ptr, csr, dinv, px);

    // layer 1 aggregation, then FUSED projection (gemm1+bn1+relu+gemm2 -> tab)
    k_gather_x<<<gN16, BLK, 0, stream>>>(px, dinv, row_ptr, csr, xa);
    k_proj_fused<<<gN16, BLK, 0, stream>>>(xa, W1, b1, g1, be1, m1, v1, W2, dinv, tab);

    // layer 2 gather + bn2 + relu + LDS pool
    k_gather_pool<<<gN16, BLK, 0, stream>>>(tab, dinv, row_ptr, csr, b2,
                                            g2, be2, m2, v2, bat, pool, cnt);

    // MLP head: one wave per graph
    k_mlp<<<NG, 64, 0, stream>>>(pool, cnt, l1W, l1b, l2W, l2b, out);
}